// Round 7
// baseline (626.743 us; speedup 1.0000x reference)
//
#include <hip/hip_runtime.h>
#include <hip/hip_bf16.h>
#include <hip/hip_fp16.h>

typedef __hip_bfloat16 bf16;
typedef __attribute__((ext_vector_type(8))) short short8;
typedef __attribute__((ext_vector_type(4))) float float4v;

#define T_  5
#define H_  64
#define W_  96
#define HW_ (H_*W_)
#define C_  256
#define NH_ 8
#define DH_ 32
#define NL_ 5
#define NP_ 4
#define LQ_ (T_*HW_)
#define UNITS_ (LQ_*NH_)          // 245760

// padded geometry: [T][66][98][256] bf16
#define PH_ 66
#define PW_ 98

static __device__ __forceinline__ void gl2lds16(const bf16* g, bf16* l){
  __builtin_amdgcn_global_load_lds(
      (const __attribute__((address_space(1))) unsigned int*)g,
      (__attribute__((address_space(3))) unsigned int*)l, 16, 0, 0);
}

// ---------------------------------------------------------------- zero fill
__global__ __launch_bounds__(256) void zfill_k(float4* __restrict__ p, int n4){
  int i = blockIdx.x*256 + threadIdx.x;
  if (i < n4){ float4 z; z.x=z.y=z.z=z.w=0.f; p[i]=z; }
}

// -------------------------------------------------- pad+cast both inputs
__global__ __launch_bounds__(256) void pad_in_k(const float* __restrict__ in0,
                                                const float* __restrict__ in1,
                                                bf16* __restrict__ pad0,
                                                bf16* __restrict__ pad1){
  __shared__ bf16 sb[256][66];
  const float* in = blockIdx.z ? in1 : in0;
  bf16* pad       = blockIdx.z ? pad1 : pad0;
  int t = blockIdx.y;
  int pix0 = blockIdx.x*64;
  int tid = threadIdx.x;
  int pl = tid & 63, cg = tid >> 6;
  #pragma unroll 4
  for (int it=0; it<64; ++it){
    int c = it*4 + cg;
    sb[c][pl] = __float2bfloat16(in[((size_t)t*C_ + c)*HW_ + pix0 + pl]);
  }
  __syncthreads();
  for (int p=0; p<64; ++p){
    int pix = pix0 + p;
    int y = pix/W_, x = pix - y*W_;
    pad[(((size_t)t*PH_ + y+1)*PW_ + x+1)*C_ + tid] = sb[tid][p];
  }
}

// ----------------------------------------------- all weight prep, one launch
#define S0_ 589824
#define S1_ 1179648
__global__ __launch_bounds__(256) void wt_all_k(const float* __restrict__ wv,
                                                const float* __restrict__ wo,
                                                const float* __restrict__ wa,
                                                const float* __restrict__ wout,
                                                const float* __restrict__ bo,
                                                const float* __restrict__ ba,
                                                bf16* __restrict__ WTv,
                                                bf16* __restrict__ WToa,
                                                bf16* __restrict__ WTout,
                                                float* __restrict__ boa){
  int idx = blockIdx.x*256 + threadIdx.x;
  if (idx < S0_){
    int n = idx/2304, r = idx - n*2304; int tap = r>>8, ci = r&255;
    WTv[idx] = __float2bfloat16(wv[((size_t)(n*C_+ci))*9 + tap]);
  } else if (idx < S0_+S1_){
    int k = idx - S0_;
    int n = k/2304, r = k - n*2304; int tap=r>>8, ci=r&255;
    float v = 0.f;
    if (n < 320)      v = wo[((size_t)(n*C_+ci))*9+tap];
    else if (n < 480) v = wa[((size_t)((n-320)*C_+ci))*9+tap];
    WToa[k] = __float2bfloat16(v);
  } else if (idx < S0_+S1_+S0_){
    int k = idx - S0_ - S1_;
    int n = k/2304, r = k - n*2304; int tap=r>>8, ci=r&255;
    WTout[k] = __float2bfloat16(wout[((size_t)(n*C_+ci))*9+tap]);
  } else if (idx < S0_+S1_+S0_+512){
    int n = idx - (S0_+S1_+S0_);
    float v = 0.f;
    if (n < 320) v = bo[n]; else if (n < 480) v = ba[n-320];
    boa[n] = v;
  }
}

// ----------------------------------------------------------- implicit GEMM
// A through LDS (global_load_lds), B direct global->VGPR (L2-hot weights).
#define BM 128
#define BN 128
#define BK 64

// fused val (by 0..1, N=256) + oa (by 2..5, N=512) conv-GEMM
__global__ __launch_bounds__(256) void gemm12_k(const bf16* __restrict__ Av,
                                                const bf16* __restrict__ Aq,
                                                const bf16* __restrict__ WTv,
                                                const bf16* __restrict__ WToa,
                                                const float* __restrict__ bv,
                                                const float* __restrict__ boa,
                                                bf16* __restrict__ outv,
                                                float* __restrict__ P,
                                                float* __restrict__ aw){
  __shared__ __align__(16) bf16 As[BM*BK];
  int tid = threadIdx.x;
  int lane = tid & 63, wvi = tid >> 6;
  int wm = wvi & 1, wn = wvi >> 1;
  int quad = lane >> 4, l15 = lane & 15;
  int bx = blockIdx.x, byy = blockIdx.y;
  bool isval = byy < 2;
  const bf16* Apad  = isval ? Av  : Aq;
  const bf16* WT    = isval ? WTv : WToa;
  const float* bias = isval ? bv  : boa;
  int nby = isval ? byy : byy - 2;

  int srow = tid >> 3;
  int c8   = (tid & 7) ^ (srow & 7);
  long abase[4];
  #pragma unroll
  for (int j=0;j<4;++j){
    int p = j*32 + srow;
    int Pm = bx*BM + p;
    int t = Pm / HW_, rem = Pm - t*HW_;
    int y = rem / W_, x = rem - y*W_;
    abase[j] = ((long)(t*PH_ + y)*PW_ + x)*C_ + c8*8;
  }
  // per-lane B row base: row = nby*BN + wn*64 + jn*16 + l15, k-lin offset quad*8
  const bf16* bq = WT + (size_t)(nby*BN + wn*64 + l15)*2304 + quad*8;

  float4v acc[4][4];
  #pragma unroll
  for (int jn=0;jn<4;++jn){
    float bvv = bias[nby*BN + wn*64 + jn*16 + l15];
    #pragma unroll
    for (int i=0;i<4;++i){ acc[i][jn][0]=bvv; acc[i][jn][1]=bvv; acc[i][jn][2]=bvv; acc[i][jn][3]=bvv; }
  }

  for (int kt=0; kt<36; ++kt){
    int tap = kt >> 2, kc = (kt & 3) << 6;
    int dy = tap/3, dx = tap - dy*3;
    long ash = (long)(dy*PW_ + dx)*C_ + kc;
    __syncthreads();
    #pragma unroll
    for (int j=0;j<4;++j)
      gl2lds16(Apad + abase[j] + ash, As + (j*256+tid)*8);
    __syncthreads();
    #pragma unroll
    for (int kk=0; kk<2; ++kk){
      short8 af[4], bfr[4];
      #pragma unroll
      for (int jn=0;jn<4;++jn)
        bfr[jn] = *(const short8*)(bq + (size_t)jn*36864 + kt*64 + kk*32);
      #pragma unroll
      for (int i=0;i<4;++i)
        af[i] = *(const short8*)(As + (wm*64 + i*16 + l15)*BK + ((((kk<<2)+quad)^(l15&7))*8));
      #pragma unroll
      for (int i=0;i<4;++i)
        #pragma unroll
        for (int jn=0;jn<4;++jn)
          acc[i][jn] = __builtin_amdgcn_mfma_f32_16x16x32_bf16(af[i], bfr[jn], acc[i][jn], 0,0,0);
    }
  }

  #pragma unroll
  for (int i=0;i<4;++i){
    int mr = bx*BM + wm*64 + i*16 + quad*4;
    #pragma unroll
    for (int jn=0;jn<4;++jn){
      int nc = nby*BN + wn*64 + jn*16 + l15;
      #pragma unroll
      for (int r=0;r<4;++r){
        float v = acc[i][jn][r];
        long m = mr + r;
        if (isval){
          outv[m*256 + nc] = __float2bfloat16(v);
        } else {
          if (nc < 320){
            int h = nc/40, rr = nc - h*40;
            int l = rr >> 3, pxy = rr & 7;
            P[((size_t)l*UNITS_ + m*8 + h)*8 + pxy] = v;
          } else if (nc < 480){
            int hh = (nc-320)/20, ii = (nc-320) - hh*20;
            aw[((size_t)m*8 + hh)*20 + ii] = v;
          }
        }
      }
    }
  }
}

// output conv: N=256, epilogue writes NCHW f32 directly
__global__ __launch_bounds__(256) void gemm_out_k(const bf16* __restrict__ Apad,
                                                  const bf16* __restrict__ WT,
                                                  const float* __restrict__ bias,
                                                  float* __restrict__ out){
  __shared__ __align__(16) bf16 As[BM*BK];
  int tid = threadIdx.x;
  int lane = tid & 63, wvi = tid >> 6;
  int wm = wvi & 1, wn = wvi >> 1;
  int quad = lane >> 4, l15 = lane & 15;
  int bx = blockIdx.x, nby = blockIdx.y;

  int srow = tid >> 3;
  int c8   = (tid & 7) ^ (srow & 7);
  long abase[4];
  #pragma unroll
  for (int j=0;j<4;++j){
    int p = j*32 + srow;
    int Pm = bx*BM + p;
    int t = Pm / HW_, rem = Pm - t*HW_;
    int y = rem / W_, x = rem - y*W_;
    abase[j] = ((long)(t*PH_ + y)*PW_ + x)*C_ + c8*8;
  }
  const bf16* bq = WT + (size_t)(nby*BN + wn*64 + l15)*2304 + quad*8;

  float4v acc[4][4];
  #pragma unroll
  for (int jn=0;jn<4;++jn){
    float bvv = bias[nby*BN + wn*64 + jn*16 + l15];
    #pragma unroll
    for (int i=0;i<4;++i){ acc[i][jn][0]=bvv; acc[i][jn][1]=bvv; acc[i][jn][2]=bvv; acc[i][jn][3]=bvv; }
  }

  for (int kt=0; kt<36; ++kt){
    int tap = kt >> 2, kc = (kt & 3) << 6;
    int dy = tap/3, dx = tap - dy*3;
    long ash = (long)(dy*PW_ + dx)*C_ + kc;
    __syncthreads();
    #pragma unroll
    for (int j=0;j<4;++j)
      gl2lds16(Apad + abase[j] + ash, As + (j*256+tid)*8);
    __syncthreads();
    #pragma unroll
    for (int kk=0; kk<2; ++kk){
      short8 af[4], bfr[4];
      #pragma unroll
      for (int jn=0;jn<4;++jn)
        bfr[jn] = *(const short8*)(bq + (size_t)jn*36864 + kt*64 + kk*32);
      #pragma unroll
      for (int i=0;i<4;++i)
        af[i] = *(const short8*)(As + (wm*64 + i*16 + l15)*BK + ((((kk<<2)+quad)^(l15&7))*8));
      #pragma unroll
      for (int i=0;i<4;++i)
        #pragma unroll
        for (int jn=0;jn<4;++jn)
          acc[i][jn] = __builtin_amdgcn_mfma_f32_16x16x32_bf16(af[i], bfr[jn], acc[i][jn], 0,0,0);
    }
  }

  int t = (bx*BM) / HW_;
  #pragma unroll
  for (int i=0;i<4;++i){
    int m = bx*BM + wm*64 + i*16 + quad*4;
    int pix = m - t*HW_;
    #pragma unroll
    for (int jn=0;jn<4;++jn){
      int nc = nby*BN + wn*64 + jn*16 + l15;
      *(float4v*)(out + ((size_t)(t*C_ + nc))*HW_ + pix) = acc[i][jn];
    }
  }
}

// ------------------------------------------------------- bilinear (zero pad)
static __device__ __forceinline__ float bilin2(const float* __restrict__ img,
                                               float px, float py){
  float x0f = floorf(px), y0f = floorf(py);
  int x0 = (int)x0f, y0 = (int)y0f;
  float fx = px - x0f, fy = py - y0f;
  int x1 = x0+1, y1 = y0+1;
  bool vx0 = (x0>=0)&&(x0<W_), vx1 = (x1>=0)&&(x1<W_);
  bool vy0 = (y0>=0)&&(y0<H_), vy1 = (y1>=0)&&(y1<H_);
  float c00 = (vx0&&vy0)? img[y0*W_+x0] : 0.f;
  float c10 = (vx1&&vy0)? img[y0*W_+x1] : 0.f;
  float c01 = (vx0&&vy1)? img[y1*W_+x0] : 0.f;
  float c11 = (vx1&&vy1)? img[y1*W_+x1] : 0.f;
  return c00*(1.f-fx)*(1.f-fy) + c10*fx*(1.f-fy) + c01*(1.f-fx)*fy + c11*fx*fy;
}

// ---------------------------------------------------------------- flow init
__global__ __launch_bounds__(256) void flow_init_k(const float* __restrict__ ff,
                                                   const float* __restrict__ fb,
                                                   float* __restrict__ flows){
  int i = blockIdx.x*256 + threadIdx.x;
  const int per = 2*HW_;
  if (i >= 7*per) return;
  int f = i/per, r = i - f*per;
  float v; int slot;
  if (f < 4) { v = ff[f*per + r]; slot = f; }
  else       { v = fb[(f-4)*per + r]; slot = 10+(f-4); }
  flows[slot*per + r] = v;
}

// ------------------------------------------------------------- flow compose
struct Comps { int dst[5]; int a[5]; int src[5]; };

__global__ __launch_bounds__(256) void flow_compose_k(float* __restrict__ flows, Comps c){
  int ci  = blockIdx.y;
  int pix = blockIdx.x*256 + threadIdx.x;
  float* D       = flows + c.dst[ci]*2*HW_;
  const float* A = flows + c.a[ci]  *2*HW_;
  const float* S = flows + c.src[ci]*2*HW_;
  float ax = A[pix], ay = A[HW_+pix];
  float px = (float)(pix % W_) + ax;
  float py = (float)(pix / W_) + ay;
  D[pix]      = ax + bilin2(S,      px, py);
  D[HW_+pix]  = ay + bilin2(S+HW_,  px, py);
}

// ---------------------------------------------------------------- prep
__device__ const int g_slotTab[25] = {
  -1,  0,  4,  5,  6,
  10, -1,  1,  7,  8,
  13, 11, -1,  2,  9,
  15, 14, 12, -1,  3,
  15, 14, 12, -1,  3 };

// per unit: softmax(aw)->w16 AND fold base into P (5 levels x 4 points RMW)
__global__ __launch_bounds__(256) void prep_k(const float* __restrict__ aw,
                                              const float* __restrict__ ref,
                                              const float* __restrict__ flows,
                                              float* __restrict__ P,
                                              __half* __restrict__ w16){
  int unit = blockIdx.x*256 + threadIdx.x;    // 245760 total
  const float4* p4 = (const float4*)(aw + (size_t)unit*20);
  float4 v[5];
  #pragma unroll
  for (int i=0;i<5;++i) v[i] = p4[i];
  float* e = (float*)v;
  float m = -1e30f;
  #pragma unroll
  for (int i=0;i<20;++i) m = fmaxf(m, e[i]);
  float s = 0.f;
  #pragma unroll
  for (int i=0;i<20;++i){ e[i] = __expf(e[i]-m); s += e[i]; }
  float inv = 1.f/s;
  __half2* o2 = (__half2*)(w16 + (size_t)unit*20);
  #pragma unroll
  for (int i=0;i<10;++i)
    o2[i] = __floats2half2_rn(e[2*i]*inv, e[2*i+1]*inv);

  int q = unit >> 3;
  int t_q = q / HW_, pix = q - t_q*HW_;
  #pragma unroll
  for (int l=0; l<NL_; ++l){
    int slot = g_slotTab[t_q*5+l];
    float ax=0.f, ay=0.f;
    if (slot >= 0){ ax = flows[slot*2*HW_ + pix]; ay = flows[slot*2*HW_ + HW_ + pix]; }
    float bx = ref[(q*5+l)*2+0]*(float)W_ - 0.5f + ax;
    float by = ref[(q*5+l)*2+1]*(float)H_ - 0.5f + ay;
    float2* pp = (float2*)(P + ((size_t)l*UNITS_ + unit)*8);
    #pragma unroll
    for (int p=0;p<4;++p){ float2 t = pp[p]; t.x += bx; t.y += by; pp[p] = t; }
  }
}

// ------------------------------------------------------- per-level sampling
template<bool FIRST, bool LAST>
__global__ __launch_bounds__(256) void phase_k(const unsigned* __restrict__ vimg0,
                                               const float2*  __restrict__ Pl,
                                               const __half*  __restrict__ wl,
                                               __half2* __restrict__ acc,
                                               bf16* __restrict__ attn_pad){
  __shared__ float4 sW[16][4];
  __shared__ int4   sI[16][4];
  int tid = threadIdx.x;
  if (tid < 64){
    int g = tid >> 2, p = tid & 3;
    int unit = blockIdx.x*16 + g;
    float2 pp = Pl[(size_t)unit*4 + p];
    float w = __half2float(wl[(size_t)unit*20 + p]);
    float x0f = floorf(pp.x), y0f = floorf(pp.y);
    float fx = pp.x - x0f,    fy = pp.y - y0f;
    int x0 = (int)x0f, y0 = (int)y0f;
    int x1 = x0+1, y1 = y0+1;
    float wx0 = 1.f-fx, wx1 = fx, wy0 = 1.f-fy, wy1 = fy;
    if ((unsigned)x0 >= (unsigned)W_) wx0 = 0.f;
    if ((unsigned)x1 >= (unsigned)W_) wx1 = 0.f;
    if ((unsigned)y0 >= (unsigned)H_) wy0 = 0.f;
    if ((unsigned)y1 >= (unsigned)H_) wy1 = 0.f;
    int xc0 = min(max(x0,0),W_-1), xc1 = min(max(x1,0),W_-1);
    int yc0 = min(max(y0,0),H_-1), yc1 = min(max(y1,0),H_-1);
    sW[g][p] = make_float4(w*wx0*wy0, w*wx1*wy0, w*wx0*wy1, w*wx1*wy1);
    sI[g][p] = make_int4((yc0*W_+xc0)*128, (yc0*W_+xc1)*128,
                         (yc1*W_+xc0)*128, (yc1*W_+xc1)*128);
  }
  __syncthreads();
  int g = tid >> 4, e = tid & 15;
  int unit = blockIdx.x*16 + g;
  int q = unit >> 3, h = unit & 7;
  const unsigned* vimg = vimg0 + h*16 + e;
  float a0, a1;
  if (FIRST){ a0 = 0.f; a1 = 0.f; }
  else { __half2 c = acc[(size_t)unit*16 + e]; a0 = __low2float(c); a1 = __high2float(c); }
  #pragma unroll
  for (int p=0; p<4; ++p){
    float4 w4 = sW[g][p];
    int4   i4 = sI[g][p];
    unsigned u00 = vimg[i4.x], u10 = vimg[i4.y];
    unsigned u01 = vimg[i4.z], u11 = vimg[i4.w];
    union {unsigned v; float f;} lo, hi;
    lo.v = u00<<16; hi.v = u00 & 0xffff0000u;
    a0 = fmaf(w4.x, lo.f, a0); a1 = fmaf(w4.x, hi.f, a1);
    lo.v = u10<<16; hi.v = u10 & 0xffff0000u;
    a0 = fmaf(w4.y, lo.f, a0); a1 = fmaf(w4.y, hi.f, a1);
    lo.v = u01<<16; hi.v = u01 & 0xffff0000u;
    a0 = fmaf(w4.z, lo.f, a0); a1 = fmaf(w4.z, hi.f, a1);
    lo.v = u11<<16; hi.v = u11 & 0xffff0000u;
    a0 = fmaf(w4.w, lo.f, a0); a1 = fmaf(w4.w, hi.f, a1);
  }
  if (LAST){
    int t_q = q / HW_, pix = q - t_q*HW_;
    int yq = pix / W_, xq = pix - yq*W_;
    union {unsigned u; bf16 hh[2];} pk;
    pk.hh[0] = __float2bfloat16(a0);
    pk.hh[1] = __float2bfloat16(a1);
    *(unsigned*)(attn_pad + (((size_t)t_q*PH_ + yq+1)*PW_ + xq+1)*C_ + h*DH_ + e*2) = pk.u;
  } else {
    acc[(size_t)unit*16 + e] = __floats2half2_rn(a0, a1);
  }
}

// ---------------------------------------------------------------- launcher
extern "C" void kernel_launch(void* const* d_in, const int* in_sizes, int n_in,
                              void* d_out, int out_size, void* d_ws, size_t ws_size,
                              hipStream_t stream) {
  const float* query   = (const float*)d_in[0];
  const float* in_flat = (const float*)d_in[1];
  const float* refpts  = (const float*)d_in[2];
  const float* ff      = (const float*)d_in[6];
  const float* fb      = (const float*)d_in[7];
  const float* w_off   = (const float*)d_in[8];
  const float* b_off   = (const float*)d_in[9];
  const float* w_attn  = (const float*)d_in[10];
  const float* b_attn  = (const float*)d_in[11];
  const float* w_val   = (const float*)d_in[12];
  const float* b_val   = (const float*)d_in[13];
  const float* w_out   = (const float*)d_in[14];
  const float* b_out   = (const float*)d_in[15];
  float* out = (float*)d_out;

  // ---- memory map (peak 113,334,272 B) ----
  char* ws = (char*)d_ws;
  bf16*  v_pad   = (bf16*) (ws + 0);            // 16,558,080  in_flat pad -> attn_pad
  bf16*  q_pad   = (bf16*) (ws + 16558080);     // 16,558,080  (dead after gemm12)
  __half* w16    = (__half*)(ws + 16558080);    //  9,830,400  (late, over dead q_pad)
  bf16*  v_val   = (bf16*) (ws + 33116160);     // 15,728,640  gather source
  float* P       = (float*)(ws + 48844800);     // 39,321,600  [5][UNITS][4][2] f32
  float* v_aw    = (float*)(ws + 88166400);     // 19,660,800  (dead after prep)
  __half2* acc   = (__half2*)(ws + 88166400);   // 15,728,640  (late, over dead v_aw)
  float* v_flows = (float*)(ws + 107827200);    //    786,432
  bf16*  WT_val  = (bf16*) (ws + 108613632);    //  1,179,648
  bf16*  WT_oa   = (bf16*) (ws + 109793280);    //  2,359,296
  bf16*  WT_out  = (bf16*) (ws + 112152576);    //  1,179,648
  float* bias_oa = (float*)(ws + 113332224);    //      2,048  -> end 113,334,272
  bf16*  attn_pad = v_pad;
  if (ws_size < (size_t)113334272) return;

  // zero both padded buffers (contiguous) in one launch
  zfill_k<<<(2069760+255)/256, 256, 0, stream>>>((float4*)v_pad, 2069760);

  // all weight prep in one launch
  wt_all_k<<<(S0_+S1_+S0_+512+255)/256, 256, 0, stream>>>(
      w_val, w_off, w_attn, w_out, b_off, b_attn, WT_val, WT_oa, WT_out, bias_oa);

  // flows
  flow_init_k<<<(7*2*HW_+255)/256, 256, 0, stream>>>(ff, fb, v_flows);
  Comps A;
  A.dst[0]=4;  A.a[0]=0;  A.src[0]=1;
  A.dst[1]=7;  A.a[1]=1;  A.src[1]=2;
  A.dst[2]=9;  A.a[2]=2;  A.src[2]=3;
  A.dst[3]=13; A.a[3]=11; A.src[3]=10;
  A.dst[4]=14; A.a[4]=12; A.src[4]=11;
  flow_compose_k<<<dim3(HW_/256,5), 256, 0, stream>>>(v_flows, A);
  Comps B;
  B.dst[0]=5;  B.a[0]=4;  B.src[0]=2;
  B.dst[1]=8;  B.a[1]=7;  B.src[1]=3;
  B.dst[2]=15; B.a[2]=14; B.src[2]=10;
  B.dst[3]=0;  B.a[3]=0;  B.src[3]=0;
  B.dst[4]=0;  B.a[4]=0;  B.src[4]=0;
  flow_compose_k<<<dim3(HW_/256,3), 256, 0, stream>>>(v_flows, B);
  Comps Cc;
  Cc.dst[0]=6; Cc.a[0]=5; Cc.src[0]=3;
  Cc.dst[1]=0; Cc.a[1]=0; Cc.src[1]=0;
  Cc.dst[2]=0; Cc.a[2]=0; Cc.src[2]=0;
  Cc.dst[3]=0; Cc.a[3]=0; Cc.src[3]=0;
  Cc.dst[4]=0; Cc.a[4]=0; Cc.src[4]=0;
  flow_compose_k<<<dim3(HW_/256,1), 256, 0, stream>>>(v_flows, Cc);

  // pad+cast both inputs, one launch
  pad_in_k<<<dim3(HW_/64, T_, 2), 256, 0, stream>>>(in_flat, query, v_pad, q_pad);

  // fused val+oa conv-GEMM (1440 blocks)
  gemm12_k<<<dim3(240, 6), 256, 0, stream>>>(v_pad, q_pad, WT_val, WT_oa,
                                             b_val, bias_oa, v_val, P, v_aw);

  // softmax + base fold, one launch
  prep_k<<<UNITS_/256, 256, 0, stream>>>(v_aw, refpts, v_flows, P, w16);

  // per-level sampling phases (L2-resident gather slices, half2 carry)
  {
    const unsigned* vb = (const unsigned*)v_val;
    phase_k<true ,false><<<UNITS_/16, 256, 0, stream>>>(vb + 0ul*HW_*128,
        (const float2*)(P + 0ul*UNITS_*8), w16 + 0,  acc, attn_pad);
    phase_k<false,false><<<UNITS_/16, 256, 0, stream>>>(vb + 1ul*HW_*128,
        (const float2*)(P + 1ul*UNITS_*8), w16 + 4,  acc, attn_pad);
    phase_k<false,false><<<UNITS_/16, 256, 0, stream>>>(vb + 2ul*HW_*128,
        (const float2*)(P + 2ul*UNITS_*8), w16 + 8,  acc, attn_pad);
    phase_k<false,false><<<UNITS_/16, 256, 0, stream>>>(vb + 3ul*HW_*128,
        (const float2*)(P + 3ul*UNITS_*8), w16 + 12, acc, attn_pad);
    phase_k<false,true ><<<UNITS_/16, 256, 0, stream>>>(vb + 4ul*HW_*128,
        (const float2*)(P + 4ul*UNITS_*8), w16 + 16, acc, attn_pad);
  }

  // output conv, direct NCHW f32 epilogue
  gemm_out_k<<<dim3(240, 2), 256, 0, stream>>>(attn_pad, WT_out, b_out, out);
}

// Round 8
// 484.764 us; speedup vs baseline: 1.2929x; 1.2929x over previous
//
#include <hip/hip_runtime.h>
#include <hip/hip_bf16.h>
#include <hip/hip_fp16.h>

typedef __hip_bfloat16 bf16;
typedef __attribute__((ext_vector_type(8))) short short8;
typedef __attribute__((ext_vector_type(4))) float float4v;

#define T_  5
#define H_  64
#define W_  96
#define HW_ (H_*W_)
#define C_  256
#define NH_ 8
#define DH_ 32
#define NL_ 5
#define NP_ 4
#define LQ_ (T_*HW_)
#define UNITS_ (LQ_*NH_)          // 245760

// padded geometry: [T][66][98][256] bf16
#define PH_ 66
#define PW_ 98

static __device__ __forceinline__ void gl2lds16(const bf16* g, bf16* l){
  __builtin_amdgcn_global_load_lds(
      (const __attribute__((address_space(1))) unsigned int*)g,
      (__attribute__((address_space(3))) unsigned int*)l, 16, 0, 0);
}

// ---------------------------------------------------------------- zero fill
__global__ __launch_bounds__(256) void zfill_k(float4* __restrict__ p, int n4){
  int i = blockIdx.x*256 + threadIdx.x;
  if (i < n4){ float4 z; z.x=z.y=z.z=z.w=0.f; p[i]=z; }
}

// -------------------------------------------------- pad+cast both inputs
__global__ __launch_bounds__(256) void pad_in_k(const float* __restrict__ in0,
                                                const float* __restrict__ in1,
                                                bf16* __restrict__ pad0,
                                                bf16* __restrict__ pad1){
  __shared__ bf16 sb[256][66];
  const float* in = blockIdx.z ? in1 : in0;
  bf16* pad       = blockIdx.z ? pad1 : pad0;
  int t = blockIdx.y;
  int pix0 = blockIdx.x*64;
  int tid = threadIdx.x;
  int pl = tid & 63, cg = tid >> 6;
  #pragma unroll 4
  for (int it=0; it<64; ++it){
    int c = it*4 + cg;
    sb[c][pl] = __float2bfloat16(in[((size_t)t*C_ + c)*HW_ + pix0 + pl]);
  }
  __syncthreads();
  for (int p=0; p<64; ++p){
    int pix = pix0 + p;
    int y = pix/W_, x = pix - y*W_;
    pad[(((size_t)t*PH_ + y+1)*PW_ + x+1)*C_ + tid] = sb[tid][p];
  }
}

// ----------------------------------------------- all weight prep, one launch
#define S0_ 589824
#define S1_ 1179648
__global__ __launch_bounds__(256) void wt_all_k(const float* __restrict__ wv,
                                                const float* __restrict__ wo,
                                                const float* __restrict__ wa,
                                                const float* __restrict__ wout,
                                                const float* __restrict__ bo,
                                                const float* __restrict__ ba,
                                                bf16* __restrict__ WTv,
                                                bf16* __restrict__ WToa,
                                                bf16* __restrict__ WTout,
                                                float* __restrict__ boa){
  int idx = blockIdx.x*256 + threadIdx.x;
  if (idx < S0_){
    int n = idx/2304, r = idx - n*2304; int tap = r>>8, ci = r&255;
    WTv[idx] = __float2bfloat16(wv[((size_t)(n*C_+ci))*9 + tap]);
  } else if (idx < S0_+S1_){
    int k = idx - S0_;
    int n = k/2304, r = k - n*2304; int tap=r>>8, ci=r&255;
    float v = 0.f;
    if (n < 320)      v = wo[((size_t)(n*C_+ci))*9+tap];
    else if (n < 480) v = wa[((size_t)((n-320)*C_+ci))*9+tap];
    WToa[k] = __float2bfloat16(v);
  } else if (idx < S0_+S1_+S0_){
    int k = idx - S0_ - S1_;
    int n = k/2304, r = k - n*2304; int tap=r>>8, ci=r&255;
    WTout[k] = __float2bfloat16(wout[((size_t)(n*C_+ci))*9+tap]);
  } else if (idx < S0_+S1_+S0_+512){
    int n = idx - (S0_+S1_+S0_);
    float v = 0.f;
    if (n < 320) v = bo[n]; else if (n < 480) v = ba[n-320];
    boa[n] = v;
  }
}

// ----------------------------------------------------------- implicit GEMM
// BM=128, BN=256, BK=64.  4 waves, wave tile 64x128 (4 i x 8 jn).
// Both operands staged via global_load_lds (XOR-swizzled, verified R4-R6).
#define BM 128
#define BN 256
#define BK 64

// fused val (byy 0, N=256) + oa (byy 1..2, N=512) conv-GEMM
__global__ __launch_bounds__(256,2) void gemm12_k(const bf16* __restrict__ Av,
                                                  const bf16* __restrict__ Aq,
                                                  const bf16* __restrict__ WTv,
                                                  const bf16* __restrict__ WToa,
                                                  const float* __restrict__ bv,
                                                  const float* __restrict__ boa,
                                                  bf16* __restrict__ outv,
                                                  float* __restrict__ P,
                                                  float* __restrict__ aw){
  __shared__ __align__(16) bf16 As[BM*BK];   // 16 KB
  __shared__ __align__(16) bf16 Bs[BN*BK];   // 32 KB
  int tid = threadIdx.x;
  int lane = tid & 63, wvi = tid >> 6;
  int wm = wvi & 1, wn = wvi >> 1;
  int quad = lane >> 4, l15 = lane & 15;
  int bx = blockIdx.x, byy = blockIdx.y;
  bool isval = byy == 0;
  const bf16* Apad  = isval ? Av  : Aq;
  const bf16* WT    = isval ? WTv : WToa;
  const float* bias = isval ? bv  : boa;
  int nby = isval ? 0 : byy - 1;

  int srow = tid >> 3;
  int c8   = (tid & 7) ^ (srow & 7);
  long abase[4];
  #pragma unroll
  for (int j=0;j<4;++j){
    int p = j*32 + srow;
    int Pm = bx*BM + p;
    int t = Pm / HW_, rem = Pm - t*HW_;
    int y = rem / W_, x = rem - y*W_;
    abase[j] = ((long)(t*PH_ + y)*PW_ + x)*C_ + c8*8;
  }
  const bf16* bbase = WT + (size_t)(nby*BN + srow)*2304 + c8*8;

  float4v acc[4][8];
  #pragma unroll
  for (int jn=0;jn<8;++jn){
    float bvv = bias[nby*BN + wn*128 + jn*16 + l15];
    #pragma unroll
    for (int i=0;i<4;++i){ acc[i][jn][0]=bvv; acc[i][jn][1]=bvv; acc[i][jn][2]=bvv; acc[i][jn][3]=bvv; }
  }

  for (int kt=0; kt<36; ++kt){
    int tap = kt >> 2, kc = (kt & 3) << 6;
    int dy = tap/3, dx = tap - dy*3;
    long ash = (long)(dy*PW_ + dx)*C_ + kc;
    long bsh = (long)kt*64;
    __syncthreads();
    #pragma unroll
    for (int j=0;j<4;++j)
      gl2lds16(Apad + abase[j] + ash, As + (j*256+tid)*8);
    #pragma unroll
    for (int j=0;j<8;++j)
      gl2lds16(bbase + (size_t)j*32*2304 + bsh, Bs + (j*256+tid)*8);
    __syncthreads();
    #pragma unroll
    for (int kk=0; kk<2; ++kk){
      int slot = ((kk<<2) + quad) ^ (l15 & 7);
      short8 af[4], bfr[8];
      #pragma unroll
      for (int jn=0;jn<8;++jn)
        bfr[jn] = *(const short8*)(Bs + (wn*128 + jn*16 + l15)*BK + slot*8);
      #pragma unroll
      for (int i=0;i<4;++i)
        af[i] = *(const short8*)(As + (wm*64 + i*16 + l15)*BK + slot*8);
      #pragma unroll
      for (int i=0;i<4;++i)
        #pragma unroll
        for (int jn=0;jn<8;++jn)
          acc[i][jn] = __builtin_amdgcn_mfma_f32_16x16x32_bf16(af[i], bfr[jn], acc[i][jn], 0,0,0);
    }
  }

  #pragma unroll
  for (int i=0;i<4;++i){
    int mr = bx*BM + wm*64 + i*16 + quad*4;
    #pragma unroll
    for (int jn=0;jn<8;++jn){
      int nc = nby*BN + wn*128 + jn*16 + l15;
      #pragma unroll
      for (int r=0;r<4;++r){
        float v = acc[i][jn][r];
        long m = mr + r;
        if (isval){
          outv[m*256 + nc] = __float2bfloat16(v);
        } else {
          if (nc < 320){
            int h = nc/40, rr = nc - h*40;
            int l = rr >> 3, pxy = rr & 7;
            P[((size_t)l*UNITS_ + m*8 + h)*8 + pxy] = v;
          } else if (nc < 480){
            int hh = (nc-320)/20, ii = (nc-320) - hh*20;
            aw[((size_t)m*8 + hh)*20 + ii] = v;
          }
        }
      }
    }
  }
}

// output conv: N=256 (one by), epilogue writes NCHW f32 directly
__global__ __launch_bounds__(256,2) void gemm_out_k(const bf16* __restrict__ Apad,
                                                    const bf16* __restrict__ WT,
                                                    const float* __restrict__ bias,
                                                    float* __restrict__ out){
  __shared__ __align__(16) bf16 As[BM*BK];
  __shared__ __align__(16) bf16 Bs[BN*BK];
  int tid = threadIdx.x;
  int lane = tid & 63, wvi = tid >> 6;
  int wm = wvi & 1, wn = wvi >> 1;
  int quad = lane >> 4, l15 = lane & 15;
  int bx = blockIdx.x;

  int srow = tid >> 3;
  int c8   = (tid & 7) ^ (srow & 7);
  long abase[4];
  #pragma unroll
  for (int j=0;j<4;++j){
    int p = j*32 + srow;
    int Pm = bx*BM + p;
    int t = Pm / HW_, rem = Pm - t*HW_;
    int y = rem / W_, x = rem - y*W_;
    abase[j] = ((long)(t*PH_ + y)*PW_ + x)*C_ + c8*8;
  }
  const bf16* bbase = WT + (size_t)srow*2304 + c8*8;

  float4v acc[4][8];
  #pragma unroll
  for (int jn=0;jn<8;++jn){
    float bvv = bias[wn*128 + jn*16 + l15];
    #pragma unroll
    for (int i=0;i<4;++i){ acc[i][jn][0]=bvv; acc[i][jn][1]=bvv; acc[i][jn][2]=bvv; acc[i][jn][3]=bvv; }
  }

  for (int kt=0; kt<36; ++kt){
    int tap = kt >> 2, kc = (kt & 3) << 6;
    int dy = tap/3, dx = tap - dy*3;
    long ash = (long)(dy*PW_ + dx)*C_ + kc;
    long bsh = (long)kt*64;
    __syncthreads();
    #pragma unroll
    for (int j=0;j<4;++j)
      gl2lds16(Apad + abase[j] + ash, As + (j*256+tid)*8);
    #pragma unroll
    for (int j=0;j<8;++j)
      gl2lds16(bbase + (size_t)j*32*2304 + bsh, Bs + (j*256+tid)*8);
    __syncthreads();
    #pragma unroll
    for (int kk=0; kk<2; ++kk){
      int slot = ((kk<<2) + quad) ^ (l15 & 7);
      short8 af[4], bfr[8];
      #pragma unroll
      for (int jn=0;jn<8;++jn)
        bfr[jn] = *(const short8*)(Bs + (wn*128 + jn*16 + l15)*BK + slot*8);
      #pragma unroll
      for (int i=0;i<4;++i)
        af[i] = *(const short8*)(As + (wm*64 + i*16 + l15)*BK + slot*8);
      #pragma unroll
      for (int i=0;i<4;++i)
        #pragma unroll
        for (int jn=0;jn<8;++jn)
          acc[i][jn] = __builtin_amdgcn_mfma_f32_16x16x32_bf16(af[i], bfr[jn], acc[i][jn], 0,0,0);
    }
  }

  int t = (bx*BM) / HW_;
  #pragma unroll
  for (int i=0;i<4;++i){
    int m = bx*BM + wm*64 + i*16 + quad*4;
    int pix = m - t*HW_;
    #pragma unroll
    for (int jn=0;jn<8;++jn){
      int nc = wn*128 + jn*16 + l15;
      *(float4v*)(out + ((size_t)(t*C_ + nc))*HW_ + pix) = acc[i][jn];
    }
  }
}

// ------------------------------------------------------- bilinear (zero pad)
static __device__ __forceinline__ float bilin2(const float* __restrict__ img,
                                               float px, float py){
  float x0f = floorf(px), y0f = floorf(py);
  int x0 = (int)x0f, y0 = (int)y0f;
  float fx = px - x0f, fy = py - y0f;
  int x1 = x0+1, y1 = y0+1;
  bool vx0 = (x0>=0)&&(x0<W_), vx1 = (x1>=0)&&(x1<W_);
  bool vy0 = (y0>=0)&&(y0<H_), vy1 = (y1>=0)&&(y1<H_);
  float c00 = (vx0&&vy0)? img[y0*W_+x0] : 0.f;
  float c10 = (vx1&&vy0)? img[y0*W_+x1] : 0.f;
  float c01 = (vx0&&vy1)? img[y1*W_+x0] : 0.f;
  float c11 = (vx1&&vy1)? img[y1*W_+x1] : 0.f;
  return c00*(1.f-fx)*(1.f-fy) + c10*fx*(1.f-fy) + c01*(1.f-fx)*fy + c11*fx*fy;
}

// ---------------------------------------------------------------- flow init
__global__ __launch_bounds__(256) void flow_init_k(const float* __restrict__ ff,
                                                   const float* __restrict__ fb,
                                                   float* __restrict__ flows){
  int i = blockIdx.x*256 + threadIdx.x;
  const int per = 2*HW_;
  if (i >= 7*per) return;
  int f = i/per, r = i - f*per;
  float v; int slot;
  if (f < 4) { v = ff[f*per + r]; slot = f; }
  else       { v = fb[(f-4)*per + r]; slot = 10+(f-4); }
  flows[slot*per + r] = v;
}

// ------------------------------------------------------------- flow compose
struct Comps { int dst[5]; int a[5]; int src[5]; };

__global__ __launch_bounds__(256) void flow_compose_k(float* __restrict__ flows, Comps c){
  int ci  = blockIdx.y;
  int pix = blockIdx.x*256 + threadIdx.x;
  float* D       = flows + c.dst[ci]*2*HW_;
  const float* A = flows + c.a[ci]  *2*HW_;
  const float* S = flows + c.src[ci]*2*HW_;
  float ax = A[pix], ay = A[HW_+pix];
  float px = (float)(pix % W_) + ax;
  float py = (float)(pix / W_) + ay;
  D[pix]      = ax + bilin2(S,      px, py);
  D[HW_+pix]  = ay + bilin2(S+HW_,  px, py);
}

// ---------------------------------------------------------------- prep
__device__ const int g_slotTab[25] = {
  -1,  0,  4,  5,  6,
  10, -1,  1,  7,  8,
  13, 11, -1,  2,  9,
  15, 14, 12, -1,  3,
  15, 14, 12, -1,  3 };

// per unit: softmax(aw)->w16 AND fold base into P (5 levels x 4 points RMW)
__global__ __launch_bounds__(256) void prep_k(const float* __restrict__ aw,
                                              const float* __restrict__ ref,
                                              const float* __restrict__ flows,
                                              float* __restrict__ P,
                                              __half* __restrict__ w16){
  int unit = blockIdx.x*256 + threadIdx.x;    // 245760 total
  const float4* p4 = (const float4*)(aw + (size_t)unit*20);
  float4 v[5];
  #pragma unroll
  for (int i=0;i<5;++i) v[i] = p4[i];
  float* e = (float*)v;
  float m = -1e30f;
  #pragma unroll
  for (int i=0;i<20;++i) m = fmaxf(m, e[i]);
  float s = 0.f;
  #pragma unroll
  for (int i=0;i<20;++i){ e[i] = __expf(e[i]-m); s += e[i]; }
  float inv = 1.f/s;
  __half2* o2 = (__half2*)(w16 + (size_t)unit*20);
  #pragma unroll
  for (int i=0;i<10;++i)
    o2[i] = __floats2half2_rn(e[2*i]*inv, e[2*i+1]*inv);

  int q = unit >> 3;
  int t_q = q / HW_, pix = q - t_q*HW_;
  #pragma unroll
  for (int l=0; l<NL_; ++l){
    int slot = g_slotTab[t_q*5+l];
    float ax=0.f, ay=0.f;
    if (slot >= 0){ ax = flows[slot*2*HW_ + pix]; ay = flows[slot*2*HW_ + HW_ + pix]; }
    float bx = ref[(q*5+l)*2+0]*(float)W_ - 0.5f + ax;
    float by = ref[(q*5+l)*2+1]*(float)H_ - 0.5f + ay;
    float2* pp = (float2*)(P + ((size_t)l*UNITS_ + unit)*8);
    #pragma unroll
    for (int p=0;p<4;++p){ float2 t = pp[p]; t.x += bx; t.y += by; pp[p] = t; }
  }
}

// ------------------------------------------------------- per-level sampling
template<bool FIRST, bool LAST>
__global__ __launch_bounds__(256) void phase_k(const unsigned* __restrict__ vimg0,
                                               const float2*  __restrict__ Pl,
                                               const __half*  __restrict__ wl,
                                               __half2* __restrict__ acc,
                                               bf16* __restrict__ attn_pad){
  __shared__ float4 sW[16][4];
  __shared__ int4   sI[16][4];
  int tid = threadIdx.x;
  if (tid < 64){
    int g = tid >> 2, p = tid & 3;
    int unit = blockIdx.x*16 + g;
    float2 pp = Pl[(size_t)unit*4 + p];
    float w = __half2float(wl[(size_t)unit*20 + p]);
    float x0f = floorf(pp.x), y0f = floorf(pp.y);
    float fx = pp.x - x0f,    fy = pp.y - y0f;
    int x0 = (int)x0f, y0 = (int)y0f;
    int x1 = x0+1, y1 = y0+1;
    float wx0 = 1.f-fx, wx1 = fx, wy0 = 1.f-fy, wy1 = fy;
    if ((unsigned)x0 >= (unsigned)W_) wx0 = 0.f;
    if ((unsigned)x1 >= (unsigned)W_) wx1 = 0.f;
    if ((unsigned)y0 >= (unsigned)H_) wy0 = 0.f;
    if ((unsigned)y1 >= (unsigned)H_) wy1 = 0.f;
    int xc0 = min(max(x0,0),W_-1), xc1 = min(max(x1,0),W_-1);
    int yc0 = min(max(y0,0),H_-1), yc1 = min(max(y1,0),H_-1);
    sW[g][p] = make_float4(w*wx0*wy0, w*wx1*wy0, w*wx0*wy1, w*wx1*wy1);
    sI[g][p] = make_int4((yc0*W_+xc0)*128, (yc0*W_+xc1)*128,
                         (yc1*W_+xc0)*128, (yc1*W_+xc1)*128);
  }
  __syncthreads();
  int g = tid >> 4, e = tid & 15;
  int unit = blockIdx.x*16 + g;
  int q = unit >> 3, h = unit & 7;
  const unsigned* vimg = vimg0 + h*16 + e;
  float a0, a1;
  if (FIRST){ a0 = 0.f; a1 = 0.f; }
  else { __half2 c = acc[(size_t)unit*16 + e]; a0 = __low2float(c); a1 = __high2float(c); }
  #pragma unroll
  for (int p=0; p<4; ++p){
    float4 w4 = sW[g][p];
    int4   i4 = sI[g][p];
    unsigned u00 = vimg[i4.x], u10 = vimg[i4.y];
    unsigned u01 = vimg[i4.z], u11 = vimg[i4.w];
    union {unsigned v; float f;} lo, hi;
    lo.v = u00<<16; hi.v = u00 & 0xffff0000u;
    a0 = fmaf(w4.x, lo.f, a0); a1 = fmaf(w4.x, hi.f, a1);
    lo.v = u10<<16; hi.v = u10 & 0xffff0000u;
    a0 = fmaf(w4.y, lo.f, a0); a1 = fmaf(w4.y, hi.f, a1);
    lo.v = u01<<16; hi.v = u01 & 0xffff0000u;
    a0 = fmaf(w4.z, lo.f, a0); a1 = fmaf(w4.z, hi.f, a1);
    lo.v = u11<<16; hi.v = u11 & 0xffff0000u;
    a0 = fmaf(w4.w, lo.f, a0); a1 = fmaf(w4.w, hi.f, a1);
  }
  if (LAST){
    int t_q = q / HW_, pix = q - t_q*HW_;
    int yq = pix / W_, xq = pix - yq*W_;
    union {unsigned u; bf16 hh[2];} pk;
    pk.hh[0] = __float2bfloat16(a0);
    pk.hh[1] = __float2bfloat16(a1);
    *(unsigned*)(attn_pad + (((size_t)t_q*PH_ + yq+1)*PW_ + xq+1)*C_ + h*DH_ + e*2) = pk.u;
  } else {
    acc[(size_t)unit*16 + e] = __floats2half2_rn(a0, a1);
  }
}

// ---------------------------------------------------------------- launcher
extern "C" void kernel_launch(void* const* d_in, const int* in_sizes, int n_in,
                              void* d_out, int out_size, void* d_ws, size_t ws_size,
                              hipStream_t stream) {
  const float* query   = (const float*)d_in[0];
  const float* in_flat = (const float*)d_in[1];
  const float* refpts  = (const float*)d_in[2];
  const float* ff      = (const float*)d_in[6];
  const float* fb      = (const float*)d_in[7];
  const float* w_off   = (const float*)d_in[8];
  const float* b_off   = (const float*)d_in[9];
  const float* w_attn  = (const float*)d_in[10];
  const float* b_attn  = (const float*)d_in[11];
  const float* w_val   = (const float*)d_in[12];
  const float* b_val   = (const float*)d_in[13];
  const float* w_out   = (const float*)d_in[14];
  const float* b_out   = (const float*)d_in[15];
  float* out = (float*)d_out;

  // ---- memory map (peak 113,334,272 B) ----
  char* ws = (char*)d_ws;
  bf16*  v_pad   = (bf16*) (ws + 0);            // 16,558,080  in_flat pad -> attn_pad
  bf16*  q_pad   = (bf16*) (ws + 16558080);     // 16,558,080  (dead after gemm12)
  __half* w16    = (__half*)(ws + 16558080);    //  9,830,400  (late, over dead q_pad)
  bf16*  v_val   = (bf16*) (ws + 33116160);     // 15,728,640  gather source
  float* P       = (float*)(ws + 48844800);     // 39,321,600  [5][UNITS][4][2] f32
  float* v_aw    = (float*)(ws + 88166400);     // 19,660,800  (dead after prep)
  __half2* acc   = (__half2*)(ws + 88166400);   // 15,728,640  (late, over dead v_aw)
  float* v_flows = (float*)(ws + 107827200);    //    786,432
  bf16*  WT_val  = (bf16*) (ws + 108613632);    //  1,179,648
  bf16*  WT_oa   = (bf16*) (ws + 109793280);    //  2,359,296
  bf16*  WT_out  = (bf16*) (ws + 112152576);    //  1,179,648
  float* bias_oa = (float*)(ws + 113332224);    //      2,048  -> end 113,334,272
  bf16*  attn_pad = v_pad;
  if (ws_size < (size_t)113334272) return;

  // zero both padded buffers (contiguous) in one launch
  zfill_k<<<(2069760+255)/256, 256, 0, stream>>>((float4*)v_pad, 2069760);

  // all weight prep in one launch
  wt_all_k<<<(S0_+S1_+S0_+512+255)/256, 256, 0, stream>>>(
      w_val, w_off, w_attn, w_out, b_off, b_attn, WT_val, WT_oa, WT_out, bias_oa);

  // flows
  flow_init_k<<<(7*2*HW_+255)/256, 256, 0, stream>>>(ff, fb, v_flows);
  Comps A;
  A.dst[0]=4;  A.a[0]=0;  A.src[0]=1;
  A.dst[1]=7;  A.a[1]=1;  A.src[1]=2;
  A.dst[2]=9;  A.a[2]=2;  A.src[2]=3;
  A.dst[3]=13; A.a[3]=11; A.src[3]=10;
  A.dst[4]=14; A.a[4]=12; A.src[4]=11;
  flow_compose_k<<<dim3(HW_/256,5), 256, 0, stream>>>(v_flows, A);
  Comps B;
  B.dst[0]=5;  B.a[0]=4;  B.src[0]=2;
  B.dst[1]=8;  B.a[1]=7;  B.src[1]=3;
  B.dst[2]=15; B.a[2]=14; B.src[2]=10;
  B.dst[3]=0;  B.a[3]=0;  B.src[3]=0;
  B.dst[4]=0;  B.a[4]=0;  B.src[4]=0;
  flow_compose_k<<<dim3(HW_/256,3), 256, 0, stream>>>(v_flows, B);
  Comps Cc;
  Cc.dst[0]=6; Cc.a[0]=5; Cc.src[0]=3;
  Cc.dst[1]=0; Cc.a[1]=0; Cc.src[1]=0;
  Cc.dst[2]=0; Cc.a[2]=0; Cc.src[2]=0;
  Cc.dst[3]=0; Cc.a[3]=0; Cc.src[3]=0;
  Cc.dst[4]=0; Cc.a[4]=0; Cc.src[4]=0;
  flow_compose_k<<<dim3(HW_/256,1), 256, 0, stream>>>(v_flows, Cc);

  // pad+cast both inputs, one launch
  pad_in_k<<<dim3(HW_/64, T_, 2), 256, 0, stream>>>(in_flat, query, v_pad, q_pad);

  // fused val+oa conv-GEMM (240 x 3 blocks)
  gemm12_k<<<dim3(240, 3), 256, 0, stream>>>(v_pad, q_pad, WT_val, WT_oa,
                                             b_val, bias_oa, v_val, P, v_aw);

  // softmax + base fold, one launch
  prep_k<<<UNITS_/256, 256, 0, stream>>>(v_aw, refpts, v_flows, P, w16);

  // per-level sampling phases (L2-resident gather slices, half2 carry)
  {
    const unsigned* vb = (const unsigned*)v_val;
    phase_k<true ,false><<<UNITS_/16, 256, 0, stream>>>(vb + 0ul*HW_*128,
        (const float2*)(P + 0ul*UNITS_*8), w16 + 0,  acc, attn_pad);
    phase_k<false,false><<<UNITS_/16, 256, 0, stream>>>(vb + 1ul*HW_*128,
        (const float2*)(P + 1ul*UNITS_*8), w16 + 4,  acc, attn_pad);
    phase_k<false,false><<<UNITS_/16, 256, 0, stream>>>(vb + 2ul*HW_*128,
        (const float2*)(P + 2ul*UNITS_*8), w16 + 8,  acc, attn_pad);
    phase_k<false,false><<<UNITS_/16, 256, 0, stream>>>(vb + 3ul*HW_*128,
        (const float2*)(P + 3ul*UNITS_*8), w16 + 12, acc, attn_pad);
    phase_k<false,true ><<<UNITS_/16, 256, 0, stream>>>(vb + 4ul*HW_*128,
        (const float2*)(P + 4ul*UNITS_*8), w16 + 16, acc, attn_pad);
  }

  // output conv, direct NCHW f32 epilogue
  gemm_out_k<<<dim3(240, 1), 256, 0, stream>>>(attn_pad, WT_out, b_out, out);
}